// Round 9
// baseline (569.835 us; speedup 1.0000x reference)
//
#include <hip/hip_runtime.h>

#define BB 2048
#define IMG 784
#define HWD 28
#define C1 32
#define C2 64
#define PP 169
#define PD 13
#define F3 10816
#define N3 2048
#define K4W 32
#define NOUT 10
#define CONV 27          // pooled-used conv2 output region is 27x27
#define PADW 30          // padded row stride (cols -1..28)
#define IMGC 29          // padded conv2 input: rows/cols -1..27
#define PLANE 13456      // 841 pixels * 16B per hh-plane
#define SCRB 418         // scr stride in shorts (dword stride 209, gcd(209,32)=1 -> full bank spread)
#define ROWB 14          // phase B starts at conv row 14

typedef unsigned long long u64;
typedef int v4i __attribute__((ext_vector_type(4)));
typedef int v16i __attribute__((ext_vector_type(16)));
typedef short s8v __attribute__((ext_vector_type(8)));

// async global->LDS, 16B per lane: LDS dest = uniform base + lane*16 (linear),
// global src is PER-LANE (pre-swizzled to match fragment layout). [m97/m173 recipe]
#define GLOAD16(gp, lp) __builtin_amdgcn_global_load_lds( \
    (__attribute__((address_space(1))) void*)(gp),        \
    (__attribute__((address_space(3))) void*)(lp), 16, 0, 0)

// ap2 magnitude, EXACT: 2^round(log2|c|). round crosses at mantissa sqrt(2).
__device__ __forceinline__ float ap2mag(float c) {
    unsigned int a = __float_as_uint(c) & 0x7fffffffu;
    unsigned int e = (a >> 23) + ((a & 0x7fffffu) > 0x3504f3u);
    return __uint_as_float(e << 23);
}
__device__ __forceinline__ float ap2sgn(float g) {
    unsigned int u = __float_as_uint(g);
    unsigned int a = u & 0x7fffffffu;
    if (a == 0) return 0.f;
    unsigned int e = (a >> 23) + ((a & 0x7fffffu) > 0x3504f3u);
    return __uint_as_float((u & 0x80000000u) | (e << 23));
}

// ---------------- stage0: conv1 mean partials + ALL weight packing ----------------
__global__ __launch_bounds__(256) void stage0(const float* __restrict__ x,
                                              const float* __restrict__ w1, const float* __restrict__ cb1,
                                              float* __restrict__ part1, float* __restrict__ w1b,
                                              const float* __restrict__ w2, char* __restrict__ w2i8,
                                              const float* __restrict__ w3, char* __restrict__ wp3i,
                                              const float* __restrict__ w4, u64* __restrict__ wp4) {
    __shared__ float xs[30 * PADW];
    __shared__ float red[4 * C1];
    int n = blockIdx.x, tid = threadIdx.x;
    int lane = tid & 63, wv = tid >> 6;
    // w3 -> i8 (grid-stride over float4 groups)
    {
        int idx = n * 256 + tid;
        int nthr = gridDim.x * 256;
        int total = (N3 * F3) / 4;
        for (int t = idx; t < total; t += nthr) {
            float4 wv4 = *(const float4*)(w3 + (size_t)t * 4);
            unsigned int w = (wv4.x >= 0.f ? 0x01u : 0xffu)
                           | (wv4.y >= 0.f ? 0x01u : 0xffu) << 8
                           | (wv4.z >= 0.f ? 0x01u : 0xffu) << 16
                           | (wv4.w >= 0.f ? 0x01u : 0xffu) << 24;
            *(unsigned int*)(wp3i + (size_t)t * 4) = w;
        }
    }
    if (n == 0) {
        for (int i = tid; i < C1 * 9; i += 256) w1b[i] = (w1[i] >= 0.f) ? 1.f : -1.f;
    } else if (n == 1) {
        // pack w2 -> i8 MFMA B-fragments: element i = (hf*9+t)*1024 + l*16 + j
        for (int i = tid; i < 2 * 9 * 64 * 16; i += 256) {
            int hf = i / 9216;
            int r = i - hf * 9216;
            int t = r >> 10;
            int l = (r >> 4) & 63;
            int j = i & 15;
            int oc = hf * 32 + (l & 31);
            int ic = ((l >> 5) << 4) + j;
            w2i8[i] = (w2[oc * 288 + ic * 9 + t] >= 0.f) ? (char)1 : (char)(-1);
        }
    } else if (n == 2) {
        for (int w = wv; w < NOUT * K4W; w += 4) {
            int o = w / K4W, j = w % K4W;
            float wvl = w4[o * N3 + j * 64 + lane];
            u64 mask = __ballot(wvl >= 0.f);
            if (lane == 0) wp4[w] = mask;
        }
    }
    // conv1 pass0 (mean partials)
    for (int i = tid; i < 30 * PADW; i += 256) {
        int r = i / PADW - 1, c = i % PADW - 1;
        float v = 0.f;
        if (r >= 0 && r < HWD && c >= 0 && c < HWD) v = x[n * IMG + r * HWD + c];
        xs[i] = v;
    }
    __syncthreads();
    bool act = tid < 196;
    int r = tid / 7, c0 = (tid % 7) * 4;
    float win[18];
#pragma unroll
    for (int k = 0; k < 18; k++) win[k] = 0.f;
    if (act) {
#pragma unroll
        for (int ry = 0; ry < 3; ry++)
#pragma unroll
            for (int cx = 0; cx < 6; cx++)
                win[ry * 6 + cx] = xs[(r + ry) * PADW + c0 + cx];
    }
#pragma unroll
    for (int ch = 0; ch < C1; ch++) {
        float a = 0.f;
        if (act) {
            float k0 = (w1[ch * 9 + 0] >= 0.f) ? 1.f : -1.f, k1 = (w1[ch * 9 + 1] >= 0.f) ? 1.f : -1.f;
            float k2 = (w1[ch * 9 + 2] >= 0.f) ? 1.f : -1.f, k3 = (w1[ch * 9 + 3] >= 0.f) ? 1.f : -1.f;
            float k4 = (w1[ch * 9 + 4] >= 0.f) ? 1.f : -1.f, k5 = (w1[ch * 9 + 5] >= 0.f) ? 1.f : -1.f;
            float k6 = (w1[ch * 9 + 6] >= 0.f) ? 1.f : -1.f, k7 = (w1[ch * 9 + 7] >= 0.f) ? 1.f : -1.f;
            float k8 = (w1[ch * 9 + 8] >= 0.f) ? 1.f : -1.f;
            float b = cb1[ch];
#pragma unroll
            for (int px = 0; px < 4; px++) {
                float s = win[px] * k0 + win[px + 1] * k1 + win[px + 2] * k2
                        + win[6 + px] * k3 + win[7 + px] * k4 + win[8 + px] * k5
                        + win[12 + px] * k6 + win[13 + px] * k7 + win[14 + px] * k8;
                a += fmaxf(s + b, 0.f);
            }
        }
        for (int off = 32; off; off >>= 1) a += __shfl_down(a, off);
        if (lane == 0) red[wv * C1 + ch] = a;
    }
    __syncthreads();
    if (tid < C1) part1[n * C1 + tid] = red[tid] + red[C1 + tid] + red[2 * C1 + tid] + red[3 * C1 + tid];
}

// ---------------- conv1 var partials ----------------
__global__ __launch_bounds__(256) void conv1_var(const float* __restrict__ x,
                            const float* __restrict__ w1b,
                            const float* __restrict__ cb1, const float* __restrict__ mean1,
                            float* __restrict__ part) {
    __shared__ float xs[30 * PADW];
    __shared__ float red[4 * C1];
    int n = blockIdx.x, tid = threadIdx.x;
    for (int i = tid; i < 30 * PADW; i += 256) {
        int r = i / PADW - 1, c = i % PADW - 1;
        float v = 0.f;
        if (r >= 0 && r < HWD && c >= 0 && c < HWD) v = x[n * IMG + r * HWD + c];
        xs[i] = v;
    }
    __syncthreads();
    bool act = tid < 196;
    int r = tid / 7, c0 = (tid % 7) * 4;
    float win[18];
#pragma unroll
    for (int k = 0; k < 18; k++) win[k] = 0.f;
    if (act) {
#pragma unroll
        for (int ry = 0; ry < 3; ry++)
#pragma unroll
            for (int cx = 0; cx < 6; cx++)
                win[ry * 6 + cx] = xs[(r + ry) * PADW + c0 + cx];
    }
    int lane = tid & 63, wv = tid >> 6;
#pragma unroll
    for (int ch = 0; ch < C1; ch++) {
        float a = 0.f;
        if (act) {
            float k0 = w1b[ch * 9 + 0], k1 = w1b[ch * 9 + 1], k2 = w1b[ch * 9 + 2];
            float k3 = w1b[ch * 9 + 3], k4 = w1b[ch * 9 + 4], k5 = w1b[ch * 9 + 5];
            float k6 = w1b[ch * 9 + 6], k7 = w1b[ch * 9 + 7], k8 = w1b[ch * 9 + 8];
            float b = cb1[ch], m = mean1[ch];
#pragma unroll
            for (int px = 0; px < 4; px++) {
                float s = win[px] * k0 + win[px + 1] * k1 + win[px + 2] * k2
                        + win[6 + px] * k3 + win[7 + px] * k4 + win[8 + px] * k5
                        + win[12 + px] * k6 + win[13 + px] * k7 + win[14 + px] * k8;
                float v = fmaxf(s + b, 0.f);
                float c = v - m;
                a += fabsf(c) * ap2mag(c);
            }
        }
        for (int off = 32; off; off >>= 1) a += __shfl_down(a, off);
        if (lane == 0) red[wv * C1 + ch] = a;
    }
    __syncthreads();
    if (tid < C1) part[n * C1 + tid] = red[tid] + red[C1 + tid] + red[2 * C1 + tid] + red[3 * C1 + tid];
}

// binarize(shift_bn(relu(conv1))) -> 32 channel bits per pixel, aligned uint4 store.
__global__ __launch_bounds__(256) void conv1_pack(const float* __restrict__ x,
                           const float* __restrict__ w1b,
                           const float* __restrict__ cb1, const float* __restrict__ mean1,
                           const float* __restrict__ scale1, const float* __restrict__ beta1,
                           unsigned int* __restrict__ s1p) {
    __shared__ float xs[30 * PADW];
    int n = blockIdx.x, tid = threadIdx.x;
    for (int i = tid; i < 30 * PADW; i += 256) {
        int r = i / PADW - 1, c = i % PADW - 1;
        float v = 0.f;
        if (r >= 0 && r < HWD && c >= 0 && c < HWD) v = x[n * IMG + r * HWD + c];
        xs[i] = v;
    }
    __syncthreads();
    if (tid >= 196) return;
    int r = tid / 7, c0 = (tid % 7) * 4;
    float win[18];
#pragma unroll
    for (int ry = 0; ry < 3; ry++)
#pragma unroll
        for (int cx = 0; cx < 6; cx++)
            win[ry * 6 + cx] = xs[(r + ry) * PADW + c0 + cx];
    unsigned int bits0 = 0, bits1 = 0, bits2 = 0, bits3 = 0;
#pragma unroll
    for (int ch = 0; ch < C1; ch++) {
        float k0 = w1b[ch * 9 + 0], k1 = w1b[ch * 9 + 1], k2 = w1b[ch * 9 + 2];
        float k3 = w1b[ch * 9 + 3], k4 = w1b[ch * 9 + 4], k5 = w1b[ch * 9 + 5];
        float k6 = w1b[ch * 9 + 6], k7 = w1b[ch * 9 + 7], k8 = w1b[ch * 9 + 8];
        float b = cb1[ch], m = mean1[ch], sc = scale1[ch], bt = beta1[ch];
#pragma unroll
        for (int px = 0; px < 4; px++) {
            float s = win[px] * k0 + win[px + 1] * k1 + win[px + 2] * k2
                    + win[6 + px] * k3 + win[7 + px] * k4 + win[8 + px] * k5
                    + win[12 + px] * k6 + win[13 + px] * k7 + win[14 + px] * k8;
            float v = fmaxf(s + b, 0.f);
            float val = sc * (v - m) + bt;
            unsigned int bit = (val >= 0.f ? 1u : 0u) << ch;
            if (px == 0) bits0 |= bit;
            else if (px == 1) bits1 |= bit;
            else if (px == 2) bits2 |= bit;
            else bits3 |= bit;
        }
    }
    uint4 w4v = make_uint4(bits0, bits1, bits2, bits3);
    *reinterpret_cast<uint4*>(&s1p[n * IMG + r * HWD + c0]) = w4v;  // 16B aligned
}

// ---------------- conv2 (i8 MFMA) + maxpool3s2 + mean partials, 1 block/sample ----------------
// R18: was LDS-capped at 2 blocks/CU (74.75 KB, Occupancy 20%) with MfmaUtil 14 /
// VALU 38 -> TLP-starved. Halve scr by splitting each oc-half into two row-phases:
// phase A = conv rows 0..14 (pool py 0..6), phase B = conv rows 14..26 (pool py
// 7..12; row 14 recomputed, +4% MFMA). LDS 74.75 -> ~54 KB -> 3 blocks/CU. Per-oc
// mean accumulators (aReg[8]) live in registers across phases; per-lane add order
// stays ascending-p (A handles p<91 terms, B the rest, both ascending) -> pm
// bit-exact, p2i integer-exact. scr stride 418 shorts (dword 209, gcd 32 = 1 ->
// full bank spread). Uniform-branch tile guards avoid wasted MFMA.
__global__ __launch_bounds__(256) void conv2pool(const unsigned int* __restrict__ s1p,
                                                 const char* __restrict__ w2i8,
                                                 const float* __restrict__ cb2,
                                                 short* __restrict__ p2i,
                                                 float* __restrict__ part2) {
    __shared__ char img[2 * PLANE];          // 26.9 KB: [hh][pixel][16] i8 planes
    __shared__ short scr[32 * SCRB];         // 26.1 KB: conv out for one phase of one oc-half
    __shared__ float pm[C2];
    int n = blockIdx.x, tid = threadIdx.x;
    int lane = tid & 63, wv = tid >> 6;
    // unpack s1p channel bits -> i8 (+1/-1); pad slots = 0 == conv zero-padding
    for (int i = tid; i < IMGC * IMGC; i += 256) {
        int r = i / IMGC, c = i - r * IMGC;  // img[r][c] = input row r-1, col c-1
        unsigned int w = 0u;
        if (r >= 1 && c >= 1) w = s1p[n * IMG + (r - 1) * HWD + (c - 1)];
        unsigned int d[8];
        if (r == 0 || c == 0) {
#pragma unroll
            for (int e = 0; e < 8; e++) d[e] = 0u;
        } else {
#pragma unroll
            for (int e = 0; e < 8; e++) {
                unsigned int nib = (w >> (4 * e)) & 0xFu;
                unsigned int t = (nib & 1u) | ((nib & 2u) << 7) | ((nib & 4u) << 14) | ((nib & 8u) << 21);
                d[e] = 0xFFFFFFFFu - t * 0xFEu;   // byte = bit ? 0x01 : 0xFF (-1)
            }
        }
        *(uint4*)&img[i * 16] = make_uint4(d[0], d[1], d[2], d[3]);            // ic 0..15  (hh=0)
        *(uint4*)&img[PLANE + i * 16] = make_uint4(d[4], d[5], d[6], d[7]);    // ic 16..31 (hh=1)
    }
    __syncthreads();
    int hh = lane >> 5;      // k-group (16 ic each)
    int l31 = lane & 31;     // A: pixel row-in-tile; D: oc column
    const char* imgp = &img[hh * PLANE];
    for (int hf = 0; hf < 2; hf++) {
        v4i bf[9];
#pragma unroll
        for (int t = 0; t < 9; t++)
            bf[t] = *(const v4i*)(w2i8 + (hf * 9 + t) * 1024 + lane * 16);
        float aReg[8];
#pragma unroll
        for (int it = 0; it < 8; it++) aReg[it] = 0.f;
#pragma unroll
        for (int ph = 0; ph < 2; ph++) {
            const int rowlo = ph ? ROWB : 0;
            const int npx = ph ? (27 - ROWB) * 27 : (ROWB + 1) * 27;   // 351 : 405
            const int ntile = (npx + 31) / 32;                          // 11 : 13
            const int pbase = rowlo * 27;
            // conv for this phase's rows
            for (int t0 = wv; t0 < ntile; t0 += 8) {
                int t1 = t0 + 4;
                bool hasB = (t1 < ntile);      // wave-uniform
                int pA = t0 * 32 + l31; if (pA > npx - 1) pA = npx - 1;
                int pB = hasB ? (t1 * 32 + l31) : 0; if (pB > npx - 1) pB = npx - 1;
                int absA = pbase + pA, absB = pbase + pB;
                int yA = absA / 27, xA = absA - yA * 27;
                int yB = absB / 27, xB = absB - yB * 27;
                int aA = (yA * IMGC + xA) * 16;
                int aB = (yB * IMGC + xB) * 16;
                v16i accA = {0,0,0,0,0,0,0,0,0,0,0,0,0,0,0,0};
                v16i accB = {0,0,0,0,0,0,0,0,0,0,0,0,0,0,0,0};
                if (hasB) {
#pragma unroll
                    for (int ky = 0; ky < 3; ky++)
#pragma unroll
                        for (int kx = 0; kx < 3; kx++) {
                            v4i fA = *(const v4i*)&imgp[aA + (ky * IMGC + kx) * 16];
                            v4i fB = *(const v4i*)&imgp[aB + (ky * IMGC + kx) * 16];
                            accA = __builtin_amdgcn_mfma_i32_32x32x32_i8(fA, bf[ky * 3 + kx], accA, 0, 0, 0);
                            accB = __builtin_amdgcn_mfma_i32_32x32x32_i8(fB, bf[ky * 3 + kx], accB, 0, 0, 0);
                        }
                } else {
#pragma unroll
                    for (int ky = 0; ky < 3; ky++)
#pragma unroll
                        for (int kx = 0; kx < 3; kx++) {
                            v4i fA = *(const v4i*)&imgp[aA + (ky * IMGC + kx) * 16];
                            accA = __builtin_amdgcn_mfma_i32_32x32x32_i8(fA, bf[ky * 3 + kx], accA, 0, 0, 0);
                        }
                }
                short* sr = &scr[l31 * SCRB];
#pragma unroll
                for (int g = 0; g < 4; g++) {
                    short4 sA;
                    sA.x = (short)accA[4 * g + 0]; sA.y = (short)accA[4 * g + 1];
                    sA.z = (short)accA[4 * g + 2]; sA.w = (short)accA[4 * g + 3];
                    *(short4*)&sr[t0 * 32 + g * 8 + 4 * hh] = sA;
                }
                if (hasB) {
#pragma unroll
                    for (int g = 0; g < 4; g++) {
                        short4 sB;
                        sB.x = (short)accB[4 * g + 0]; sB.y = (short)accB[4 * g + 1];
                        sB.z = (short)accB[4 * g + 2]; sB.w = (short)accB[4 * g + 3];
                        *(short4*)&sr[t1 * 32 + g * 8 + 4 * hh] = sB;
                    }
                }
            }
            __syncthreads();
            // maxpool 3x3 s2 + bias/relu mean accumulation for this phase's pool rows
            const int pyLo = ph ? 7 : 0, pyHi = ph ? 12 : 6;
#pragma unroll
            for (int it = 0; it < 8; it++) {
                int ol = wv + 4 * it;
                int oc = hf * 32 + ol;
                float b = cb2[oc];
                for (int p = lane; p < PP; p += 64) {
                    int py = p / PD;
                    if (py < pyLo || py > pyHi) continue;
                    int px = p - py * PD;
                    const short* rr = &scr[ol * SCRB + (2 * py - rowlo) * CONV + 2 * px];
                    int m0 = max(max((int)rr[0], (int)rr[1]), (int)rr[2]);
                    int m1 = max(max((int)rr[CONV], (int)rr[CONV + 1]), (int)rr[CONV + 2]);
                    int m2 = max(max((int)rr[2 * CONV], (int)rr[2 * CONV + 1]), (int)rr[2 * CONV + 2]);
                    int val = max(max(m0, m1), m2);
                    p2i[n * F3 + oc * PP + p] = (short)val;
                    aReg[it] += fmaxf((float)val + b, 0.f);
                }
            }
            __syncthreads();
        }
        // reduce per-oc accumulators (same shfl tree as before -> bit-exact)
#pragma unroll
        for (int it = 0; it < 8; it++) {
            float a = aReg[it];
            for (int off = 32; off; off >>= 1) a += __shfl_down(a, off);
            if (lane == 0) pm[hf * 32 + wv + 4 * it] = a;
        }
    }
    __syncthreads();
    if (tid < C2) part2[n * C2 + tid] = pm[tid];
}

// ---------------- p2 var partials ----------------
// R18: p2i reads were 2B/lane at 128B stride (uncoalesced). Stage the sample's
// whole row (21.6 KB) into LDS via coalesced uint4 loads, then run the IDENTICAL
// loops/order from LDS (consecutive-short reads = conflict-free). Bit-exact.
__global__ __launch_bounds__(256) void p2_var(const short* __restrict__ p2i,
                         const float* __restrict__ cb2,
                         const float* __restrict__ mean2, float* __restrict__ part) {
    __shared__ short rows[F3];               // 21.6 KB
    int n = blockIdx.x, tid = threadIdx.x, lane = tid & 63, wv = tid >> 6;
    {
        const uint4* src = (const uint4*)(p2i + (size_t)n * F3);   // 16B aligned (F3*2 = 21632)
        uint4* dst = (uint4*)rows;
        for (int i = tid; i < (F3 * 2) / 16; i += 256) dst[i] = src[i];
    }
    __syncthreads();
    __shared__ float red[C2];
#pragma unroll
    for (int i = 0; i < 16; i++) {
        int ch = wv * 16 + i;
        const short* row = rows + ch * PP;
        float b = cb2[ch];
        float m = mean2[ch];
        float a = 0.f;
        for (int p = lane; p < PP; p += 64) {
            float v = fmaxf((float)row[p] + b, 0.f);
            float c = v - m;
            a += fabsf(c) * ap2mag(c);
        }
        for (int off = 32; off; off >>= 1) a += __shfl_down(a, off);
        if (lane == 0) red[ch] = a;
    }
    __syncthreads();
    if (tid < C2) part[n * C2 + tid] = red[tid];
}

// ---------------- stage-2 reduce: mean or ap2-scale ----------------
__global__ __launch_bounds__(256) void reduce_stats(const float* __restrict__ part, int nch, int nblk,
                             const float* __restrict__ g, float* __restrict__ outv,
                             int mode, double count) {
    int ch = blockIdx.x, tid = threadIdx.x;
    double a = 0.0;
    for (int i = tid; i < nblk; i += 256) a += (double)part[(size_t)i * nch + ch];
    __shared__ double red[4];
    for (int off = 32; off; off >>= 1) a += __shfl_down(a, off);
    int lane = tid & 63, wv = tid >> 6;
    if (lane == 0) red[wv] = a;
    __syncthreads();
    if (tid == 0) {
        double s = red[0] + red[1] + red[2] + red[3];
        if (mode == 0) {
            outv[ch] = (float)(s / count);
        } else {
            float var = (float)(s / count);
            float inv = 1.0f / sqrtf(var + 1e-4f);
            outv[ch] = ap2sgn(g[ch]) * ap2mag(inv);
        }
    }
}

// binarize layer-2 -> i8 (+1/-1) plane [BB][F3] for MFMA lin3
// R18: short8 (b128) vector load + uint2 store instead of 4 scalar short loads.
// Per-element float math unchanged (independent elements) -> bit-exact.
__global__ __launch_bounds__(256) void p2_packi8(const short* __restrict__ p2i, const float* __restrict__ cb2,
                        const float* __restrict__ mean2, const float* __restrict__ scale2,
                        const float* __restrict__ beta2, char* __restrict__ hp3i) {
    int idx = blockIdx.x * 256 + threadIdx.x;
    int nthr = gridDim.x * 256;
    int total = (BB * F3) / 8;
    for (int t = idx; t < total; t += nthr) {
        size_t base = (size_t)t * 8;
        int f0 = (int)(base % F3);             // F3 % 8 == 0 -> group never crosses a row
        s8v s8 = *(const s8v*)(p2i + base);    // 16B aligned
        unsigned int w0 = 0, w1 = 0;
#pragma unroll
        for (int e = 0; e < 8; e++) {
            int f = f0 + e;
            int oc = f / PP;
            float v = fmaxf((float)s8[e] + cb2[oc], 0.f);
            float val = scale2[oc] * (v - mean2[oc]) + beta2[oc];
            unsigned int byte = (val >= 0.f) ? 0x01u : 0xffu;
            if (e < 4) w0 |= byte << (8 * e);
            else       w1 |= byte << (8 * (e - 4));
        }
        *(uint2*)(hp3i + base) = make_uint2(w0, w1);   // 8B aligned
    }
}

// ---------------- lin3: i8 MFMA GEMM, 128x128 tile, SPLIT-K x2 (R16, verified) ----------------
__global__ __launch_bounds__(512) void lin3_mfma(const char* __restrict__ hp3i,
                                                 const char* __restrict__ wp3i,
                                                 int* __restrict__ cpart) {
    __shared__ v4i aL[2][1024];   // 2 bufs x (2 ksteps x 8 rowgroups x 64 frags) = 32 KB
    __shared__ v4i bL[2][1024];   // 32 KB   -> 64 KB total => 2 blocks/CU
    int tid = threadIdx.x;
    int lane = tid & 63, wv = tid >> 6;       // 8 waves
    int wr = wv >> 2, wc = wv & 3;            // 2 x 4 wave grid
    int m0 = blockIdx.y * 128, n0 = blockIdx.x * 128;
    int kp = blockIdx.z;
    int kbase = kp ? 5440 : 0;
    int NC = kp ? 42 : 43;        // 128B chunks (kpart0: 42 full + half chunk 42)
    int lastks = kp ? 2 : 1;
    // per-lane gather offset: row = rg*16 + (lane&15), k-quarter = (lane>>4)*16
    int loff = (lane & 15) * F3 + (lane >> 4) * 16;
    const char* gA = hp3i + (size_t)(m0 + wv * 16) * F3 + kbase + loff;   // A rowgroup wv
    const char* gB = wp3i + (size_t)(n0 + wv * 16) * F3 + kbase + loff;   // B rowgroup wv
    v4i acc[4][2];
#pragma unroll
    for (int i = 0; i < 4; i++)
#pragma unroll
        for (int j = 0; j < 2; j++) acc[i][j] = (v4i){0, 0, 0, 0};

    auto stage = [&](int c) {   // 4 gloads/wave: A rg=wv (ks0,ks1), B rg=wv (ks0,ks1)
        int b = c & 1;
        const char* pA = gA + (size_t)c * 128;
        const char* pB = gB + (size_t)c * 128;
        char* dA = (char*)&aL[b][0] + wv * 1024;
        char* dB = (char*)&bL[b][0] + wv * 1024;
        GLOAD16(pA,      dA);          // ks0 stripe wv
        GLOAD16(pA + 64, dA + 8192);   // ks1 stripe 8+wv
        GLOAD16(pB,      dB);
        GLOAD16(pB + 64, dB + 8192);
    };
    auto compute = [&](int c, int nks) {
        int b = c & 1;
        for (int ks = 0; ks < nks; ++ks) {
            v4i af[4], bf[2];
#pragma unroll
            for (int i = 0; i < 4; i++) af[i] = aL[b][ks * 512 + (wr * 4 + i) * 64 + lane];
#pragma unroll
            for (int j = 0; j < 2; j++) bf[j] = bL[b][ks * 512 + (wc * 2 + j) * 64 + lane];
            __builtin_amdgcn_s_setprio(1);
#pragma unroll
            for (int i = 0; i < 4; i++)
#pragma unroll
                for (int j = 0; j < 2; j++)
                    acc[i][j] = __builtin_amdgcn_mfma_i32_16x16x64_i8(af[i], bf[j], acc[i][j], 0, 0, 0);
            __builtin_amdgcn_s_setprio(0);
        }
    };

    stage(0);
    __syncthreads();
    for (int c = 0; c < NC; ++c) {
        if (c < NC - 1) stage(c + 1);
        compute(c, (c == NC - 1) ? lastks : 2);
        __syncthreads();
    }
    // store i32 partial tile, coalesced: slot = (i*2+j)*512 + tid (16B/lane)
    int* cp = cpart + ((size_t)kp * 256 + (size_t)blockIdx.y * 16 + blockIdx.x) * 16384;
#pragma unroll
    for (int i = 0; i < 4; i++)
#pragma unroll
        for (int j = 0; j < 2; j++)
            *(v4i*)&cp[(((i * 2 + j) * 512) + tid) * 4] = acc[i][j];
}

// ---------------- lin3_fin: integer-combine kparts + verified epilogue ----------------
__global__ __launch_bounds__(512) void lin3_fin(const int* __restrict__ cpart,
                                                const float* __restrict__ b3l,
                                                float* __restrict__ h3,
                                                float* __restrict__ h3T,
                                                float* __restrict__ part3) {
    __shared__ float csr[8][32];
    int tid = threadIdx.x;
    int lane = tid & 63, wv = tid >> 6;
    int wr = wv >> 2, wc = wv & 3;
    int m0 = blockIdx.y * 128, n0 = blockIdx.x * 128;
    const int* c0 = cpart + ((size_t)blockIdx.y * 16 + blockIdx.x) * 16384;
    const int* c1 = c0 + (size_t)256 * 16384;
    v4i acc[4][2];
#pragma unroll
    for (int i = 0; i < 4; i++)
#pragma unroll
        for (int j = 0; j < 2; j++) {
            int s = (((i * 2 + j) * 512) + tid) * 4;
            v4i a = *(const v4i*)&c0[s];
            v4i b = *(const v4i*)&c1[s];
            acc[i][j] = a + b;    // integer add: exact, order-free
        }
    int q = lane >> 4, m16 = lane & 15;
    float cs[2] = {0.f, 0.f};
#pragma unroll
    for (int j = 0; j < 2; j++) {
        int col = n0 + wc * 32 + j * 16 + m16;
        float bias = b3l[col];
#pragma unroll
        for (int i = 0; i < 4; i++) {
            int rowb = m0 + wr * 64 + i * 16 + q * 4;
            float4 t4;
#pragma unroll
            for (int rg = 0; rg < 4; rg++) {
                float v = fmaxf((float)acc[i][j][rg] + bias, 0.f);
                h3[(size_t)(rowb + rg) * N3 + col] = v;
                ((float*)&t4)[rg] = v;
                cs[j] += v;
            }
            *(float4*)&h3T[(size_t)col * BB + rowb] = t4;   // 16B aligned (rowb % 4 == 0)
        }
    }
#pragma unroll
    for (int j = 0; j < 2; j++) {
        cs[j] += __shfl_xor(cs[j], 16);
        cs[j] += __shfl_xor(cs[j], 32);
        if (lane < 16) csr[wv][j * 16 + m16] = cs[j];
    }
    __syncthreads();
    if (tid < 128) {
        int wcg = tid >> 5, cc = tid & 31;   // column group (=wc), index
        part3[(size_t)blockIdx.y * N3 + n0 + tid] = csr[wcg][cc] + csr[4 + wcg][cc];
    }
}

// ---------------- h3: mean + var + scale, one kernel per column ----------------
__global__ __launch_bounds__(256) void h3_finish(const float* __restrict__ h3T,
                                                 const float* __restrict__ part3,
                                                 const float* __restrict__ g3,
                                                 float* __restrict__ mean3, float* __restrict__ scale3) {
    int nn = blockIdx.x, tid = threadIdx.x;
    __shared__ float msh;
    __shared__ double redd[4];
    if (tid < 64) {
        float a = (tid < 16) ? part3[(size_t)tid * N3 + nn] : 0.f;
        for (int off = 8; off; off >>= 1) a += __shfl_down(a, off);
        if (tid == 0) { float m = a / (float)BB; mean3[nn] = m; msh = m; }
    }
    __syncthreads();
    float m = msh;
    float acc = 0.f;
#pragma unroll
    for (int q = 0; q < 8; q++) {
        float v = h3T[(size_t)nn * BB + q * 256 + tid];
        float c = v - m;
        acc += fabsf(c) * ap2mag(c);
    }
    double a = (double)acc;
    for (int off = 32; off; off >>= 1) a += __shfl_down(a, off);
    int lane = tid & 63, wv = tid >> 6;
    if (lane == 0) redd[wv] = a;
    __syncthreads();
    if (tid == 0) {
        float var = (float)((redd[0] + redd[1] + redd[2] + redd[3]) / (double)BB);
        float inv = 1.0f / sqrtf(var + 1e-4f);
        scale3[nn] = ap2sgn(g3[nn]) * ap2mag(inv);
    }
}

// ---------------- fused h3 binarize + lin4 (one block per sample) ----------------
__global__ __launch_bounds__(256) void h4_out(const float* __restrict__ h3,
                                              const float* __restrict__ mean3, const float* __restrict__ scale3,
                                              const float* __restrict__ bt3,
                                              const u64* __restrict__ wp4, const float* __restrict__ b4,
                                              float* __restrict__ out) {
    __shared__ u64 hb[K4W];
    __shared__ u64 wsh[NOUT * 33];
    int m = blockIdx.x, tid = threadIdx.x, lane = tid & 63, wv = tid >> 6;
    for (int i = tid; i < NOUT * K4W; i += 256) wsh[(i / K4W) * 33 + (i % K4W)] = wp4[i];
#pragma unroll
    for (int q = 0; q < 8; q++) {
        int j = wv * 8 + q;
        int f = j * 64 + lane;
        float v = h3[(size_t)m * N3 + f];
        float val = scale3[f] * (v - mean3[f]) + bt3[f];
        u64 mask = __ballot(val >= 0.f);
        if (lane == 0) hb[j] = mask;
    }
    __syncthreads();
    if (tid < NOUT) {
        int c = 0;
#pragma unroll
        for (int k = 0; k < K4W; k++) c += (int)__popcll(hb[k] ^ wsh[tid * 33 + k]);
        out[m * NOUT + tid] = (float)(N3 - 2 * c) + b4[tid];
    }
}

extern "C" void kernel_launch(void* const* d_in, const int* in_sizes, int n_in,
                              void* d_out, int out_size, void* d_ws, size_t ws_size,
                              hipStream_t stream) {
    const float* x   = (const float*)d_in[0];
    const float* w1  = (const float*)d_in[1];
    const float* cb1 = (const float*)d_in[2];
    const float* g1  = (const float*)d_in[3];
    const float* bt1 = (const float*)d_in[4];
    const float* w2  = (const float*)d_in[5];
    const float* cb2 = (const float*)d_in[6];
    const float* g2  = (const float*)d_in[7];
    const float* bt2 = (const float*)d_in[8];
    const float* w3  = (const float*)d_in[9];
    const float* b3l = (const float*)d_in[10];
    const float* g3  = (const float*)d_in[11];
    const float* bt3 = (const float*)d_in[12];
    const float* w4  = (const float*)d_in[13];
    const float* b4l = (const float*)d_in[14];
    float* out = (float*)d_out;

    char* base = (char*)d_ws;
    size_t off = 0;
    auto carve = [&](size_t bytes) { char* p = base + off; off = (off + bytes + 255) & ~(size_t)255; return p; };
    // lifetime-aliased buffers:
    char* bufA = carve((size_t)BB * C2 * PP * 2);   // p2i (44.3 MB); h3 + h3T alias (p2i dead after p2_packi8)
    char* bufB = carve((size_t)BB * F3);            // hp3i (22.2 MB); s1p aliases (dead before p2_packi8)
    char* bufC = carve((size_t)N3 * F3);            // wp3i (22.2 MB)
    short* p2i         = (short*)bufA;
    float* h3          = (float*)bufA;
    float* h3T         = (float*)(bufA + (size_t)BB * N3 * 4);   // 16.8 MB, fits in bufA's 44.3 MB
    char* hp3i         = bufB;
    unsigned int* s1p  = (unsigned int*)bufB;
    char* wp3i         = bufC;
    int* cpart         = (int*)carve((size_t)2 * BB * N3 * 4);   // 33.6 MB split-K partials
    u64* wp4           = (u64*)carve((size_t)NOUT * K4W * 8);
    char* w2i8         = (char*)carve((size_t)2 * 9 * 64 * 16);
    float* w1b         = (float*)carve((size_t)C1 * 9 * 4);
    float* part1       = (float*)carve((size_t)BB * C1 * 4);
    float* part2       = (float*)carve((size_t)BB * C2 * 4);
    float* part3       = (float*)carve((size_t)16 * N3 * 4);
    float* fstats      = (float*)carve((size_t)(32 + 32 + 64 + 64 + 2048 + 2048) * 4);
    float* mean1 = fstats;          float* scale1 = fstats + 32;
    float* mean2 = fstats + 64;     float* scale2 = fstats + 128;
    float* mean3 = fstats + 192;    float* scale3 = fstats + 2240;

    stage0<<<BB, 256, 0, stream>>>(x, w1, cb1, part1, w1b, w2, w2i8, w3, wp3i, w4, wp4);
    reduce_stats<<<C1, 256, 0, stream>>>(part1, C1, BB, g1, mean1, 0, (double)BB * IMG);
    conv1_var<<<BB, 256, 0, stream>>>(x, w1b, cb1, mean1, part1);
    reduce_stats<<<C1, 256, 0, stream>>>(part1, C1, BB, g1, scale1, 1, (double)BB * IMG);
    conv1_pack<<<BB, 256, 0, stream>>>(x, w1b, cb1, mean1, scale1, bt1, s1p);
    conv2pool<<<BB, 256, 0, stream>>>(s1p, w2i8, cb2, p2i, part2);
    reduce_stats<<<C2, 256, 0, stream>>>(part2, C2, BB, g2, mean2, 0, (double)BB * PP);
    p2_var<<<BB, 256, 0, stream>>>(p2i, cb2, mean2, part2);
    reduce_stats<<<C2, 256, 0, stream>>>(part2, C2, BB, g2, scale2, 1, (double)BB * PP);
    p2_packi8<<<2048, 256, 0, stream>>>(p2i, cb2, mean2, scale2, bt2, hp3i);
    lin3_mfma<<<dim3(16, 16, 2), 512, 0, stream>>>(hp3i, wp3i, cpart);
    lin3_fin<<<dim3(16, 16), 512, 0, stream>>>(cpart, b3l, h3, h3T, part3);
    h3_finish<<<N3, 256, 0, stream>>>(h3T, part3, g3, mean3, scale3);
    h4_out<<<BB, 256, 0, stream>>>(h3, mean3, scale3, bt3, wp4, b4l, out);

    (void)in_sizes; (void)n_in; (void)out_size; (void)ws_size;
}

// Round 10
// 507.261 us; speedup vs baseline: 1.1234x; 1.1234x over previous
//
#include <hip/hip_runtime.h>

#define BB 2048
#define IMG 784
#define HWD 28
#define C1 32
#define C2 64
#define PP 169
#define PD 13
#define F3 10816
#define N3 2048
#define K4W 32
#define NOUT 10
#define CONV 27          // pooled-used conv2 output region is 27x27
#define PADW 30          // padded row stride (cols -1..28)
#define IMGC 29          // padded conv2 input: rows/cols -1..27
#define PLANE 13456      // 841 pixels * 16B per hh-plane
#define SCRP 740         // scr stride in shorts

typedef unsigned long long u64;
typedef int v4i __attribute__((ext_vector_type(4)));
typedef int v16i __attribute__((ext_vector_type(16)));
typedef short s8v __attribute__((ext_vector_type(8)));

// async global->LDS, 16B per lane: LDS dest = uniform base + lane*16 (linear),
// global src is PER-LANE (pre-swizzled to match fragment layout). [m97/m173 recipe]
#define GLOAD16(gp, lp) __builtin_amdgcn_global_load_lds( \
    (__attribute__((address_space(1))) void*)(gp),        \
    (__attribute__((address_space(3))) void*)(lp), 16, 0, 0)

// ap2 magnitude, EXACT: 2^round(log2|c|). round crosses at mantissa sqrt(2).
__device__ __forceinline__ float ap2mag(float c) {
    unsigned int a = __float_as_uint(c) & 0x7fffffffu;
    unsigned int e = (a >> 23) + ((a & 0x7fffffu) > 0x3504f3u);
    return __uint_as_float(e << 23);
}
__device__ __forceinline__ float ap2sgn(float g) {
    unsigned int u = __float_as_uint(g);
    unsigned int a = u & 0x7fffffffu;
    if (a == 0) return 0.f;
    unsigned int e = (a >> 23) + ((a & 0x7fffffu) > 0x3504f3u);
    return __uint_as_float((u & 0x80000000u) | (e << 23));
}

// ---------------- stage0: conv1 mean partials + ALL weight packing ----------------
__global__ __launch_bounds__(256) void stage0(const float* __restrict__ x,
                                              const float* __restrict__ w1, const float* __restrict__ cb1,
                                              float* __restrict__ part1, float* __restrict__ w1b,
                                              const float* __restrict__ w2, char* __restrict__ w2i8,
                                              const float* __restrict__ w3, char* __restrict__ wp3i,
                                              const float* __restrict__ w4, u64* __restrict__ wp4) {
    __shared__ float xs[30 * PADW];
    __shared__ float red[4 * C1];
    int n = blockIdx.x, tid = threadIdx.x;
    int lane = tid & 63, wv = tid >> 6;
    // w3 -> i8 (grid-stride over float4 groups)
    {
        int idx = n * 256 + tid;
        int nthr = gridDim.x * 256;
        int total = (N3 * F3) / 4;
        for (int t = idx; t < total; t += nthr) {
            float4 wv4 = *(const float4*)(w3 + (size_t)t * 4);
            unsigned int w = (wv4.x >= 0.f ? 0x01u : 0xffu)
                           | (wv4.y >= 0.f ? 0x01u : 0xffu) << 8
                           | (wv4.z >= 0.f ? 0x01u : 0xffu) << 16
                           | (wv4.w >= 0.f ? 0x01u : 0xffu) << 24;
            *(unsigned int*)(wp3i + (size_t)t * 4) = w;
        }
    }
    if (n == 0) {
        for (int i = tid; i < C1 * 9; i += 256) w1b[i] = (w1[i] >= 0.f) ? 1.f : -1.f;
    } else if (n == 1) {
        // pack w2 -> i8 MFMA B-fragments: element i = (hf*9+t)*1024 + l*16 + j
        for (int i = tid; i < 2 * 9 * 64 * 16; i += 256) {
            int hf = i / 9216;
            int r = i - hf * 9216;
            int t = r >> 10;
            int l = (r >> 4) & 63;
            int j = i & 15;
            int oc = hf * 32 + (l & 31);
            int ic = ((l >> 5) << 4) + j;
            w2i8[i] = (w2[oc * 288 + ic * 9 + t] >= 0.f) ? (char)1 : (char)(-1);
        }
    } else if (n == 2) {
        for (int w = wv; w < NOUT * K4W; w += 4) {
            int o = w / K4W, j = w % K4W;
            float wvl = w4[o * N3 + j * 64 + lane];
            u64 mask = __ballot(wvl >= 0.f);
            if (lane == 0) wp4[w] = mask;
        }
    }
    // conv1 pass0 (mean partials)
    for (int i = tid; i < 30 * PADW; i += 256) {
        int r = i / PADW - 1, c = i % PADW - 1;
        float v = 0.f;
        if (r >= 0 && r < HWD && c >= 0 && c < HWD) v = x[n * IMG + r * HWD + c];
        xs[i] = v;
    }
    __syncthreads();
    bool act = tid < 196;
    int r = tid / 7, c0 = (tid % 7) * 4;
    float win[18];
#pragma unroll
    for (int k = 0; k < 18; k++) win[k] = 0.f;
    if (act) {
#pragma unroll
        for (int ry = 0; ry < 3; ry++)
#pragma unroll
            for (int cx = 0; cx < 6; cx++)
                win[ry * 6 + cx] = xs[(r + ry) * PADW + c0 + cx];
    }
#pragma unroll
    for (int ch = 0; ch < C1; ch++) {
        float a = 0.f;
        if (act) {
            float k0 = (w1[ch * 9 + 0] >= 0.f) ? 1.f : -1.f, k1 = (w1[ch * 9 + 1] >= 0.f) ? 1.f : -1.f;
            float k2 = (w1[ch * 9 + 2] >= 0.f) ? 1.f : -1.f, k3 = (w1[ch * 9 + 3] >= 0.f) ? 1.f : -1.f;
            float k4 = (w1[ch * 9 + 4] >= 0.f) ? 1.f : -1.f, k5 = (w1[ch * 9 + 5] >= 0.f) ? 1.f : -1.f;
            float k6 = (w1[ch * 9 + 6] >= 0.f) ? 1.f : -1.f, k7 = (w1[ch * 9 + 7] >= 0.f) ? 1.f : -1.f;
            float k8 = (w1[ch * 9 + 8] >= 0.f) ? 1.f : -1.f;
            float b = cb1[ch];
#pragma unroll
            for (int px = 0; px < 4; px++) {
                float s = win[px] * k0 + win[px + 1] * k1 + win[px + 2] * k2
                        + win[6 + px] * k3 + win[7 + px] * k4 + win[8 + px] * k5
                        + win[12 + px] * k6 + win[13 + px] * k7 + win[14 + px] * k8;
                a += fmaxf(s + b, 0.f);
            }
        }
        for (int off = 32; off; off >>= 1) a += __shfl_down(a, off);
        if (lane == 0) red[wv * C1 + ch] = a;
    }
    __syncthreads();
    if (tid < C1) part1[n * C1 + tid] = red[tid] + red[C1 + tid] + red[2 * C1 + tid] + red[3 * C1 + tid];
}

// ---------------- conv1 var partials ----------------
__global__ __launch_bounds__(256) void conv1_var(const float* __restrict__ x,
                            const float* __restrict__ w1b,
                            const float* __restrict__ cb1, const float* __restrict__ mean1,
                            float* __restrict__ part) {
    __shared__ float xs[30 * PADW];
    __shared__ float red[4 * C1];
    int n = blockIdx.x, tid = threadIdx.x;
    for (int i = tid; i < 30 * PADW; i += 256) {
        int r = i / PADW - 1, c = i % PADW - 1;
        float v = 0.f;
        if (r >= 0 && r < HWD && c >= 0 && c < HWD) v = x[n * IMG + r * HWD + c];
        xs[i] = v;
    }
    __syncthreads();
    bool act = tid < 196;
    int r = tid / 7, c0 = (tid % 7) * 4;
    float win[18];
#pragma unroll
    for (int k = 0; k < 18; k++) win[k] = 0.f;
    if (act) {
#pragma unroll
        for (int ry = 0; ry < 3; ry++)
#pragma unroll
            for (int cx = 0; cx < 6; cx++)
                win[ry * 6 + cx] = xs[(r + ry) * PADW + c0 + cx];
    }
    int lane = tid & 63, wv = tid >> 6;
#pragma unroll
    for (int ch = 0; ch < C1; ch++) {
        float a = 0.f;
        if (act) {
            float k0 = w1b[ch * 9 + 0], k1 = w1b[ch * 9 + 1], k2 = w1b[ch * 9 + 2];
            float k3 = w1b[ch * 9 + 3], k4 = w1b[ch * 9 + 4], k5 = w1b[ch * 9 + 5];
            float k6 = w1b[ch * 9 + 6], k7 = w1b[ch * 9 + 7], k8 = w1b[ch * 9 + 8];
            float b = cb1[ch], m = mean1[ch];
#pragma unroll
            for (int px = 0; px < 4; px++) {
                float s = win[px] * k0 + win[px + 1] * k1 + win[px + 2] * k2
                        + win[6 + px] * k3 + win[7 + px] * k4 + win[8 + px] * k5
                        + win[12 + px] * k6 + win[13 + px] * k7 + win[14 + px] * k8;
                float v = fmaxf(s + b, 0.f);
                float c = v - m;
                a += fabsf(c) * ap2mag(c);
            }
        }
        for (int off = 32; off; off >>= 1) a += __shfl_down(a, off);
        if (lane == 0) red[wv * C1 + ch] = a;
    }
    __syncthreads();
    if (tid < C1) part[n * C1 + tid] = red[tid] + red[C1 + tid] + red[2 * C1 + tid] + red[3 * C1 + tid];
}

// binarize(shift_bn(relu(conv1))) -> 32 channel bits per pixel, aligned uint4 store.
__global__ __launch_bounds__(256) void conv1_pack(const float* __restrict__ x,
                           const float* __restrict__ w1b,
                           const float* __restrict__ cb1, const float* __restrict__ mean1,
                           const float* __restrict__ scale1, const float* __restrict__ beta1,
                           unsigned int* __restrict__ s1p) {
    __shared__ float xs[30 * PADW];
    int n = blockIdx.x, tid = threadIdx.x;
    for (int i = tid; i < 30 * PADW; i += 256) {
        int r = i / PADW - 1, c = i % PADW - 1;
        float v = 0.f;
        if (r >= 0 && r < HWD && c >= 0 && c < HWD) v = x[n * IMG + r * HWD + c];
        xs[i] = v;
    }
    __syncthreads();
    if (tid >= 196) return;
    int r = tid / 7, c0 = (tid % 7) * 4;
    float win[18];
#pragma unroll
    for (int ry = 0; ry < 3; ry++)
#pragma unroll
        for (int cx = 0; cx < 6; cx++)
            win[ry * 6 + cx] = xs[(r + ry) * PADW + c0 + cx];
    unsigned int bits0 = 0, bits1 = 0, bits2 = 0, bits3 = 0;
#pragma unroll
    for (int ch = 0; ch < C1; ch++) {
        float k0 = w1b[ch * 9 + 0], k1 = w1b[ch * 9 + 1], k2 = w1b[ch * 9 + 2];
        float k3 = w1b[ch * 9 + 3], k4 = w1b[ch * 9 + 4], k5 = w1b[ch * 9 + 5];
        float k6 = w1b[ch * 9 + 6], k7 = w1b[ch * 9 + 7], k8 = w1b[ch * 9 + 8];
        float b = cb1[ch], m = mean1[ch], sc = scale1[ch], bt = beta1[ch];
#pragma unroll
        for (int px = 0; px < 4; px++) {
            float s = win[px] * k0 + win[px + 1] * k1 + win[px + 2] * k2
                    + win[6 + px] * k3 + win[7 + px] * k4 + win[8 + px] * k5
                    + win[12 + px] * k6 + win[13 + px] * k7 + win[14 + px] * k8;
            float v = fmaxf(s + b, 0.f);
            float val = sc * (v - m) + bt;
            unsigned int bit = (val >= 0.f ? 1u : 0u) << ch;
            if (px == 0) bits0 |= bit;
            else if (px == 1) bits1 |= bit;
            else if (px == 2) bits2 |= bit;
            else bits3 |= bit;
        }
    }
    uint4 w4v = make_uint4(bits0, bits1, bits2, bits3);
    *reinterpret_cast<uint4*>(&s1p[n * IMG + r * HWD + c0]) = w4v;  // 16B aligned
}

// ---------------- conv2 (i8 MFMA) + maxpool3s2 + mean partials, 1 block/sample ----------------
// R19: REVERT to the verified R17 structure (R18's phase-split regressed 84->145us:
// occupancy didn't move, conflicts didn't move, barriers doubled). One change vs
// R17: pool windows read as 6 LDS ops (aligned b32 pairs + u16) instead of 9 scalar
// u16 -- row starts are provably even/odd/even short indices, so each row's 3
// shorts = 1 b32 + 1 u16. Integer-identical values; float accumulation order
// unchanged -> bit-exact. Pool LDS issue time (the dominant ~10k cyc/block) -33%.
__global__ __launch_bounds__(256) void conv2pool(const unsigned int* __restrict__ s1p,
                                                 const char* __restrict__ w2i8,
                                                 const float* __restrict__ cb2,
                                                 short* __restrict__ p2i,
                                                 float* __restrict__ part2) {
    __shared__ char img[2 * PLANE];          // 26.9 KB: [hh][pixel][16] i8 planes
    __shared__ short scr[32 * SCRP];         // 46.3 KB: conv out for one oc-half, [oc][pixel]
    __shared__ float pm[C2];
    int n = blockIdx.x, tid = threadIdx.x;
    int lane = tid & 63, wv = tid >> 6;
    // unpack s1p channel bits -> i8 (+1/-1); pad slots = 0 == conv zero-padding
    for (int i = tid; i < IMGC * IMGC; i += 256) {
        int r = i / IMGC, c = i - r * IMGC;  // img[r][c] = input row r-1, col c-1
        unsigned int w = 0u;
        if (r >= 1 && c >= 1) w = s1p[n * IMG + (r - 1) * HWD + (c - 1)];
        unsigned int d[8];
        if (r == 0 || c == 0) {
#pragma unroll
            for (int e = 0; e < 8; e++) d[e] = 0u;
        } else {
#pragma unroll
            for (int e = 0; e < 8; e++) {
                unsigned int nib = (w >> (4 * e)) & 0xFu;
                unsigned int t = (nib & 1u) | ((nib & 2u) << 7) | ((nib & 4u) << 14) | ((nib & 8u) << 21);
                d[e] = 0xFFFFFFFFu - t * 0xFEu;   // byte = bit ? 0x01 : 0xFF (-1)
            }
        }
        *(uint4*)&img[i * 16] = make_uint4(d[0], d[1], d[2], d[3]);            // ic 0..15  (hh=0)
        *(uint4*)&img[PLANE + i * 16] = make_uint4(d[4], d[5], d[6], d[7]);    // ic 16..31 (hh=1)
    }
    __syncthreads();
    int hh = lane >> 5;      // k-group (16 ic each)
    int l31 = lane & 31;     // A: pixel row-in-tile; D: oc column
    const char* imgp = &img[hh * PLANE];
    for (int hf = 0; hf < 2; hf++) {
        v4i bf[9];
#pragma unroll
        for (int t = 0; t < 9; t++)
            bf[t] = *(const v4i*)(w2i8 + (hf * 9 + t) * 1024 + lane * 16);
        // 23 m-tiles of 32 pixels; wave wv owns {wv, wv+4, ...}; 2 tiles in flight
#pragma unroll
        for (int j = 0; j < 3; j++) {
            int mtA = wv + 8 * j, mtB = mtA + 4;   // mtA <= 19 always valid; mtB==23 -> no store
            int pA = mtA * 32 + l31; if (pA > 728) pA = 728;
            int pB = mtB * 32 + l31; if (pB > 728) pB = 728;
            int yA = pA / 27, xA = pA - yA * 27;
            int yB = pB / 27, xB = pB - yB * 27;
            int aA = (yA * IMGC + xA) * 16;
            int aB = (yB * IMGC + xB) * 16;
            v16i accA = {0,0,0,0,0,0,0,0,0,0,0,0,0,0,0,0};
            v16i accB = {0,0,0,0,0,0,0,0,0,0,0,0,0,0,0,0};
#pragma unroll
            for (int ky = 0; ky < 3; ky++)
#pragma unroll
                for (int kx = 0; kx < 3; kx++) {
                    v4i fA = *(const v4i*)&imgp[aA + (ky * IMGC + kx) * 16];
                    v4i fB = *(const v4i*)&imgp[aB + (ky * IMGC + kx) * 16];
                    accA = __builtin_amdgcn_mfma_i32_32x32x32_i8(fA, bf[ky * 3 + kx], accA, 0, 0, 0);
                    accB = __builtin_amdgcn_mfma_i32_32x32x32_i8(fB, bf[ky * 3 + kx], accB, 0, 0, 0);
                }
            short* sr = &scr[l31 * SCRP];
#pragma unroll
            for (int g = 0; g < 4; g++) {
                short4 sA;
                sA.x = (short)accA[4 * g + 0]; sA.y = (short)accA[4 * g + 1];
                sA.z = (short)accA[4 * g + 2]; sA.w = (short)accA[4 * g + 3];
                *(short4*)&sr[mtA * 32 + g * 8 + 4 * hh] = sA;
            }
            if (mtB < 23) {
#pragma unroll
                for (int g = 0; g < 4; g++) {
                    short4 sB;
                    sB.x = (short)accB[4 * g + 0]; sB.y = (short)accB[4 * g + 1];
                    sB.z = (short)accB[4 * g + 2]; sB.w = (short)accB[4 * g + 3];
                    *(short4*)&sr[mtB * 32 + g * 8 + 4 * hh] = sB;
                }
            }
        }
        __syncthreads();
        // maxpool 3x3 s2 + bias/relu mean partials, direct, 8 ols/wave.
        // Window rows fetched as b32+u16 (6 LDS ops vs 9). Base short index
        // ol*SCRP + 54py + 2px is EVEN -> row0/row2 start 4B-aligned; row1
        // starts odd -> u16 then b32 at +1. Integer-exact.
        for (int ol = wv; ol < 32; ol += 4) {
            int oc = hf * 32 + ol;
            float b = cb2[oc];
            float a = 0.f;
            for (int p = lane; p < PP; p += 64) {
                int py = p / PD, px = p - py * PD;
                const short* rr = &scr[ol * SCRP + (2 * py) * CONV + 2 * px];
                // row 0 (even start)
                unsigned int u0 = *(const unsigned int*)rr;
                int m0 = max(max((int)(short)(u0 & 0xFFFF), (int)(short)(u0 >> 16)), (int)rr[2]);
                // row 1 (odd start): u16 at 27, b32 at 28
                unsigned int u1 = *(const unsigned int*)(rr + CONV + 1);
                int m1 = max(max((int)rr[CONV], (int)(short)(u1 & 0xFFFF)), (int)(short)(u1 >> 16));
                // row 2 (even start)
                unsigned int u2 = *(const unsigned int*)(rr + 2 * CONV);
                int m2 = max(max((int)(short)(u2 & 0xFFFF), (int)(short)(u2 >> 16)), (int)rr[2 * CONV + 2]);
                int val = max(max(m0, m1), m2);
                p2i[n * F3 + oc * PP + p] = (short)val;
                a += fmaxf((float)val + b, 0.f);
            }
            for (int off = 32; off; off >>= 1) a += __shfl_down(a, off);
            if (lane == 0) pm[oc] = a;
        }
        __syncthreads();
    }
    if (tid < C2) part2[n * C2 + tid] = pm[tid];
}

// ---------------- p2 var partials (LDS-staged, coalesced reads; R18-verified) ----------------
__global__ __launch_bounds__(256) void p2_var(const short* __restrict__ p2i,
                         const float* __restrict__ cb2,
                         const float* __restrict__ mean2, float* __restrict__ part) {
    __shared__ short rows[F3];               // 21.6 KB
    int n = blockIdx.x, tid = threadIdx.x, lane = tid & 63, wv = tid >> 6;
    {
        const uint4* src = (const uint4*)(p2i + (size_t)n * F3);   // 16B aligned (F3*2 = 21632)
        uint4* dst = (uint4*)rows;
        for (int i = tid; i < (F3 * 2) / 16; i += 256) dst[i] = src[i];
    }
    __syncthreads();
    __shared__ float red[C2];
#pragma unroll
    for (int i = 0; i < 16; i++) {
        int ch = wv * 16 + i;
        const short* row = rows + ch * PP;
        float b = cb2[ch];
        float m = mean2[ch];
        float a = 0.f;
        for (int p = lane; p < PP; p += 64) {
            float v = fmaxf((float)row[p] + b, 0.f);
            float c = v - m;
            a += fabsf(c) * ap2mag(c);
        }
        for (int off = 32; off; off >>= 1) a += __shfl_down(a, off);
        if (lane == 0) red[ch] = a;
    }
    __syncthreads();
    if (tid < C2) part[n * C2 + tid] = red[tid];
}

// ---------------- stage-2 reduce: mean or ap2-scale ----------------
__global__ __launch_bounds__(256) void reduce_stats(const float* __restrict__ part, int nch, int nblk,
                             const float* __restrict__ g, float* __restrict__ outv,
                             int mode, double count) {
    int ch = blockIdx.x, tid = threadIdx.x;
    double a = 0.0;
    for (int i = tid; i < nblk; i += 256) a += (double)part[(size_t)i * nch + ch];
    __shared__ double red[4];
    for (int off = 32; off; off >>= 1) a += __shfl_down(a, off);
    int lane = tid & 63, wv = tid >> 6;
    if (lane == 0) red[wv] = a;
    __syncthreads();
    if (tid == 0) {
        double s = red[0] + red[1] + red[2] + red[3];
        if (mode == 0) {
            outv[ch] = (float)(s / count);
        } else {
            float var = (float)(s / count);
            float inv = 1.0f / sqrtf(var + 1e-4f);
            outv[ch] = ap2sgn(g[ch]) * ap2mag(inv);
        }
    }
}

// binarize layer-2 -> i8 (+1/-1) plane [BB][F3] for MFMA lin3 (vectorized, R18-verified)
__global__ __launch_bounds__(256) void p2_packi8(const short* __restrict__ p2i, const float* __restrict__ cb2,
                        const float* __restrict__ mean2, const float* __restrict__ scale2,
                        const float* __restrict__ beta2, char* __restrict__ hp3i) {
    int idx = blockIdx.x * 256 + threadIdx.x;
    int nthr = gridDim.x * 256;
    int total = (BB * F3) / 8;
    for (int t = idx; t < total; t += nthr) {
        size_t base = (size_t)t * 8;
        int f0 = (int)(base % F3);             // F3 % 8 == 0 -> group never crosses a row
        s8v s8 = *(const s8v*)(p2i + base);    // 16B aligned
        unsigned int w0 = 0, w1 = 0;
#pragma unroll
        for (int e = 0; e < 8; e++) {
            int f = f0 + e;
            int oc = f / PP;
            float v = fmaxf((float)s8[e] + cb2[oc], 0.f);
            float val = scale2[oc] * (v - mean2[oc]) + beta2[oc];
            unsigned int byte = (val >= 0.f) ? 0x01u : 0xffu;
            if (e < 4) w0 |= byte << (8 * e);
            else       w1 |= byte << (8 * (e - 4));
        }
        *(uint2*)(hp3i + base) = make_uint2(w0, w1);   // 8B aligned
    }
}

// ---------------- lin3: i8 MFMA GEMM, 128x128 tile, SPLIT-K x2 (R16, verified) ----------------
__global__ __launch_bounds__(512) void lin3_mfma(const char* __restrict__ hp3i,
                                                 const char* __restrict__ wp3i,
                                                 int* __restrict__ cpart) {
    __shared__ v4i aL[2][1024];   // 2 bufs x (2 ksteps x 8 rowgroups x 64 frags) = 32 KB
    __shared__ v4i bL[2][1024];   // 32 KB   -> 64 KB total => 2 blocks/CU
    int tid = threadIdx.x;
    int lane = tid & 63, wv = tid >> 6;       // 8 waves
    int wr = wv >> 2, wc = wv & 3;            // 2 x 4 wave grid
    int m0 = blockIdx.y * 128, n0 = blockIdx.x * 128;
    int kp = blockIdx.z;
    int kbase = kp ? 5440 : 0;
    int NC = kp ? 42 : 43;        // 128B chunks (kpart0: 42 full + half chunk 42)
    int lastks = kp ? 2 : 1;
    // per-lane gather offset: row = rg*16 + (lane&15), k-quarter = (lane>>4)*16
    int loff = (lane & 15) * F3 + (lane >> 4) * 16;
    const char* gA = hp3i + (size_t)(m0 + wv * 16) * F3 + kbase + loff;   // A rowgroup wv
    const char* gB = wp3i + (size_t)(n0 + wv * 16) * F3 + kbase + loff;   // B rowgroup wv
    v4i acc[4][2];
#pragma unroll
    for (int i = 0; i < 4; i++)
#pragma unroll
        for (int j = 0; j < 2; j++) acc[i][j] = (v4i){0, 0, 0, 0};

    auto stage = [&](int c) {   // 4 gloads/wave: A rg=wv (ks0,ks1), B rg=wv (ks0,ks1)
        int b = c & 1;
        const char* pA = gA + (size_t)c * 128;
        const char* pB = gB + (size_t)c * 128;
        char* dA = (char*)&aL[b][0] + wv * 1024;
        char* dB = (char*)&bL[b][0] + wv * 1024;
        GLOAD16(pA,      dA);          // ks0 stripe wv
        GLOAD16(pA + 64, dA + 8192);   // ks1 stripe 8+wv
        GLOAD16(pB,      dB);
        GLOAD16(pB + 64, dB + 8192);
    };
    auto compute = [&](int c, int nks) {
        int b = c & 1;
        for (int ks = 0; ks < nks; ++ks) {
            v4i af[4], bf[2];
#pragma unroll
            for (int i = 0; i < 4; i++) af[i] = aL[b][ks * 512 + (wr * 4 + i) * 64 + lane];
#pragma unroll
            for (int j = 0; j < 2; j++) bf[j] = bL[b][ks * 512 + (wc * 2 + j) * 64 + lane];
            __builtin_amdgcn_s_setprio(1);
#pragma unroll
            for (int i = 0; i < 4; i++)
#pragma unroll
                for (int j = 0; j < 2; j++)
                    acc[i][j] = __builtin_amdgcn_mfma_i32_16x16x64_i8(af[i], bf[j], acc[i][j], 0, 0, 0);
            __builtin_amdgcn_s_setprio(0);
        }
    };

    stage(0);
    __syncthreads();
    for (int c = 0; c < NC; ++c) {
        if (c < NC - 1) stage(c + 1);
        compute(c, (c == NC - 1) ? lastks : 2);
        __syncthreads();
    }
    // store i32 partial tile, coalesced: slot = (i*2+j)*512 + tid (16B/lane)
    int* cp = cpart + ((size_t)kp * 256 + (size_t)blockIdx.y * 16 + blockIdx.x) * 16384;
#pragma unroll
    for (int i = 0; i < 4; i++)
#pragma unroll
        for (int j = 0; j < 2; j++)
            *(v4i*)&cp[(((i * 2 + j) * 512) + tid) * 4] = acc[i][j];
}

// ---------------- lin3_fin: integer-combine kparts + verified epilogue ----------------
__global__ __launch_bounds__(512) void lin3_fin(const int* __restrict__ cpart,
                                                const float* __restrict__ b3l,
                                                float* __restrict__ h3,
                                                float* __restrict__ h3T,
                                                float* __restrict__ part3) {
    __shared__ float csr[8][32];
    int tid = threadIdx.x;
    int lane = tid & 63, wv = tid >> 6;
    int wr = wv >> 2, wc = wv & 3;
    int m0 = blockIdx.y * 128, n0 = blockIdx.x * 128;
    const int* c0 = cpart + ((size_t)blockIdx.y * 16 + blockIdx.x) * 16384;
    const int* c1 = c0 + (size_t)256 * 16384;
    v4i acc[4][2];
#pragma unroll
    for (int i = 0; i < 4; i++)
#pragma unroll
        for (int j = 0; j < 2; j++) {
            int s = (((i * 2 + j) * 512) + tid) * 4;
            v4i a = *(const v4i*)&c0[s];
            v4i b = *(const v4i*)&c1[s];
            acc[i][j] = a + b;    // integer add: exact, order-free
        }
    int q = lane >> 4, m16 = lane & 15;
    float cs[2] = {0.f, 0.f};
#pragma unroll
    for (int j = 0; j < 2; j++) {
        int col = n0 + wc * 32 + j * 16 + m16;
        float bias = b3l[col];
#pragma unroll
        for (int i = 0; i < 4; i++) {
            int rowb = m0 + wr * 64 + i * 16 + q * 4;
            float4 t4;
#pragma unroll
            for (int rg = 0; rg < 4; rg++) {
                float v = fmaxf((float)acc[i][j][rg] + bias, 0.f);
                h3[(size_t)(rowb + rg) * N3 + col] = v;
                ((float*)&t4)[rg] = v;
                cs[j] += v;
            }
            *(float4*)&h3T[(size_t)col * BB + rowb] = t4;   // 16B aligned (rowb % 4 == 0)
        }
    }
#pragma unroll
    for (int j = 0; j < 2; j++) {
        cs[j] += __shfl_xor(cs[j], 16);
        cs[j] += __shfl_xor(cs[j], 32);
        if (lane < 16) csr[wv][j * 16 + m16] = cs[j];
    }
    __syncthreads();
    if (tid < 128) {
        int wcg = tid >> 5, cc = tid & 31;   // column group (=wc), index
        part3[(size_t)blockIdx.y * N3 + n0 + tid] = csr[wcg][cc] + csr[4 + wcg][cc];
    }
}

// ---------------- h3: mean + var + scale, one kernel per column ----------------
__global__ __launch_bounds__(256) void h3_finish(const float* __restrict__ h3T,
                                                 const float* __restrict__ part3,
                                                 const float* __restrict__ g3,
                                                 float* __restrict__ mean3, float* __restrict__ scale3) {
    int nn = blockIdx.x, tid = threadIdx.x;
    __shared__ float msh;
    __shared__ double redd[4];
    if (tid < 64) {
        float a = (tid < 16) ? part3[(size_t)tid * N3 + nn] : 0.f;
        for (int off = 8; off; off >>= 1) a += __shfl_down(a, off);
        if (tid == 0) { float m = a / (float)BB; mean3[nn] = m; msh = m; }
    }
    __syncthreads();
    float m = msh;
    float acc = 0.f;
#pragma unroll
    for (int q = 0; q < 8; q++) {
        float v = h3T[(size_t)nn * BB + q * 256 + tid];
        float c = v - m;
        acc += fabsf(c) * ap2mag(c);
    }
    double a = (double)acc;
    for (int off = 32; off; off >>= 1) a += __shfl_down(a, off);
    int lane = tid & 63, wv = tid >> 6;
    if (lane == 0) redd[wv] = a;
    __syncthreads();
    if (tid == 0) {
        float var = (float)((redd[0] + redd[1] + redd[2] + redd[3]) / (double)BB);
        float inv = 1.0f / sqrtf(var + 1e-4f);
        scale3[nn] = ap2sgn(g3[nn]) * ap2mag(inv);
    }
}

// ---------------- fused h3 binarize + lin4 (one block per sample) ----------------
__global__ __launch_bounds__(256) void h4_out(const float* __restrict__ h3,
                                              const float* __restrict__ mean3, const float* __restrict__ scale3,
                                              const float* __restrict__ bt3,
                                              const u64* __restrict__ wp4, const float* __restrict__ b4,
                                              float* __restrict__ out) {
    __shared__ u64 hb[K4W];
    __shared__ u64 wsh[NOUT * 33];
    int m = blockIdx.x, tid = threadIdx.x, lane = tid & 63, wv = tid >> 6;
    for (int i = tid; i < NOUT * K4W; i += 256) wsh[(i / K4W) * 33 + (i % K4W)] = wp4[i];
#pragma unroll
    for (int q = 0; q < 8; q++) {
        int j = wv * 8 + q;
        int f = j * 64 + lane;
        float v = h3[(size_t)m * N3 + f];
        float val = scale3[f] * (v - mean3[f]) + bt3[f];
        u64 mask = __ballot(val >= 0.f);
        if (lane == 0) hb[j] = mask;
    }
    __syncthreads();
    if (tid < NOUT) {
        int c = 0;
#pragma unroll
        for (int k = 0; k < K4W; k++) c += (int)__popcll(hb[k] ^ wsh[tid * 33 + k]);
        out[m * NOUT + tid] = (float)(N3 - 2 * c) + b4[tid];
    }
}

extern "C" void kernel_launch(void* const* d_in, const int* in_sizes, int n_in,
                              void* d_out, int out_size, void* d_ws, size_t ws_size,
                              hipStream_t stream) {
    const float* x   = (const float*)d_in[0];
    const float* w1  = (const float*)d_in[1];
    const float* cb1 = (const float*)d_in[2];
    const float* g1  = (const float*)d_in[3];
    const float* bt1 = (const float*)d_in[4];
    const float* w2  = (const float*)d_in[5];
    const float* cb2 = (const float*)d_in[6];
    const float* g2  = (const float*)d_in[7];
    const float* bt2 = (const float*)d_in[8];
    const float* w3  = (const float*)d_in[9];
    const float* b3l = (const float*)d_in[10];
    const float* g3  = (const float*)d_in[11];
    const float* bt3 = (const float*)d_in[12];
    const float* w4  = (const float*)d_in[13];
    const float* b4l = (const float*)d_in[14];
    float* out = (float*)d_out;

    char* base = (char*)d_ws;
    size_t off = 0;
    auto carve = [&](size_t bytes) { char* p = base + off; off = (off + bytes + 255) & ~(size_t)255; return p; };
    // lifetime-aliased buffers:
    char* bufA = carve((size_t)BB * C2 * PP * 2);   // p2i (44.3 MB); h3 + h3T alias (p2i dead after p2_packi8)
    char* bufB = carve((size_t)BB * F3);            // hp3i (22.2 MB); s1p aliases (dead before p2_packi8)
    char* bufC = carve((size_t)N3 * F3);            // wp3i (22.2 MB)
    short* p2i         = (short*)bufA;
    float* h3          = (float*)bufA;
    float* h3T         = (float*)(bufA + (size_t)BB * N3 * 4);   // 16.8 MB, fits in bufA's 44.3 MB
    char* hp3i         = bufB;
    unsigned int* s1p  = (unsigned int*)bufB;
    char* wp3i         = bufC;
    int* cpart         = (int*)carve((size_t)2 * BB * N3 * 4);   // 33.6 MB split-K partials
    u64* wp4           = (u64*)carve((size_t)NOUT * K4W * 8);
    char* w2i8         = (char*)carve((size_t)2 * 9 * 64 * 16);
    float* w1b         = (float*)carve((size_t)C1 * 9 * 4);
    float* part1       = (float*)carve((size_t)BB * C1 * 4);
    float* part2       = (float*)carve((size_t)BB * C2 * 4);
    float* part3       = (float*)carve((size_t)16 * N3 * 4);
    float* fstats      = (float*)carve((size_t)(32 + 32 + 64 + 64 + 2048 + 2048) * 4);
    float* mean1 = fstats;          float* scale1 = fstats + 32;
    float* mean2 = fstats + 64;     float* scale2 = fstats + 128;
    float* mean3 = fstats + 192;    float* scale3 = fstats + 2240;

    stage0<<<BB, 256, 0, stream>>>(x, w1, cb1, part1, w1b, w2, w2i8, w3, wp3i, w4, wp4);
    reduce_stats<<<C1, 256, 0, stream>>>(part1, C1, BB, g1, mean1, 0, (double)BB * IMG);
    conv1_var<<<BB, 256, 0, stream>>>(x, w1b, cb1, mean1, part1);
    reduce_stats<<<C1, 256, 0, stream>>>(part1, C1, BB, g1, scale1, 1, (double)BB * IMG);
    conv1_pack<<<BB, 256, 0, stream>>>(x, w1b, cb1, mean1, scale1, bt1, s1p);
    conv2pool<<<BB, 256, 0, stream>>>(s1p, w2i8, cb2, p2i, part2);
    reduce_stats<<<C2, 256, 0, stream>>>(part2, C2, BB, g2, mean2, 0, (double)BB * PP);
    p2_var<<<BB, 256, 0, stream>>>(p2i, cb2, mean2, part2);
    reduce_stats<<<C2, 256, 0, stream>>>(part2, C2, BB, g2, scale2, 1, (double)BB * PP);
    p2_packi8<<<2048, 256, 0, stream>>>(p2i, cb2, mean2, scale2, bt2, hp3i);
    lin3_mfma<<<dim3(16, 16, 2), 512, 0, stream>>>(hp3i, wp3i, cpart);
    lin3_fin<<<dim3(16, 16), 512, 0, stream>>>(cpart, b3l, h3, h3T, part3);
    h3_finish<<<N3, 256, 0, stream>>>(h3T, part3, g3, mean3, scale3);
    h4_out<<<BB, 256, 0, stream>>>(h3, mean3, scale3, bt3, wp4, b4l, out);

    (void)in_sizes; (void)n_in; (void)out_size; (void)ws_size;
}